// Round 1
// baseline (119.423 us; speedup 1.0000x reference)
//
#include <hip/hip_runtime.h>

typedef short bf16x8 __attribute__((ext_vector_type(8)));
typedef float f32x4 __attribute__((ext_vector_type(4)));

#define LN_EPS 1e-5f
#define SLOPE 0.2f

__device__ __forceinline__ float bf2f(unsigned short s){
  return __uint_as_float(((unsigned)s) << 16);
}
__device__ __forceinline__ unsigned short f2bf(float f){
  unsigned u = __float_as_uint(f);
  u += 0x7fffu + ((u >> 16) & 1u);   // round-to-nearest-even
  return (unsigned short)(u >> 16);
}

// Pre-convert W_l|W_r (256x256 f32 each) into bf16 slice image in ws:
// element ((s*4+g)*512 + c)*8 + j  =  W[k = s*32+g*8+j][c]   (c<256: W_l, else W_r)
// This is exactly the linear LDS image global_load_lds needs per K-slice.
__global__ void wconv_kernel(const float* __restrict__ Wl,
                             const float* __restrict__ Wr,
                             unsigned short* __restrict__ wbf){
  int idx = blockIdx.x * 256 + threadIdx.x;   // 0..131071
  int j = idx & 7;
  int c = (idx >> 3) & 511;
  int g = (idx >> 12) & 3;
  int s = idx >> 14;
  int k = s * 32 + g * 8 + j;
  float v = (c < 256) ? Wl[k * 256 + c] : Wr[k * 256 + (c - 256)];
  wbf[idx] = f2bf(v);
}

// Fused: [g_l|g_r] = h @ [W_l|W_r] (bf16 MFMA) -> attention -> LayerNorm.
// 16 batches per workgroup (64 rows), 4 waves, wave w owns cols [w*128, w*128+128).
template<bool USE_WS>
__global__ __launch_bounds__(256, 2)
void gat_fused(const float* __restrict__ hin, const float* __restrict__ ebias,
               const float* __restrict__ Wl, const float* __restrict__ Wr,
               const float* __restrict__ avec, const float* __restrict__ gmw,
               const float* __restrict__ btw, const unsigned short* __restrict__ wbf,
               float* __restrict__ out){
  // LDS: GEMM phase: h tile [64][256] bf16 (32KB, XOR-swizzled) + W slice image (32KB)
  //      attn phase: g tile [64][512] bf16 (64KB) overlays both (after barrier)
  __shared__ __align__(16) unsigned short lds[32768];
  __shared__ float a_s[256];
  __shared__ float eb_s[16];
  const int t = threadIdx.x;
  const int lane = t & 63;
  const int w = t >> 6;
  const int b0 = blockIdx.x * 16;

  a_s[t] = avec[t];
  if (t < 16) eb_s[t] = ebias[t];

  // ---- stage h tile (64 rows x 256 k) f32->bf16, XOR-swizzled by row&7 (16B units)
  {
    const float* hb = hin + (size_t)b0 * 1024;
    #pragma unroll
    for (int it = 0; it < 8; ++it){
      int q = it * 256 + t;          // 16B-chunk id, 2048 total
      int row = q >> 5;
      int c = q & 31;
      const float* src = hb + row * 256 + c * 8;
      float4 f0 = *(const float4*)src;
      float4 f1 = *(const float4*)(src + 4);
      bf16x8 v;
      v[0]=f2bf(f0.x); v[1]=f2bf(f0.y); v[2]=f2bf(f0.z); v[3]=f2bf(f0.w);
      v[4]=f2bf(f1.x); v[5]=f2bf(f1.y); v[6]=f2bf(f1.z); v[7]=f2bf(f1.w);
      *(bf16x8*)&lds[row * 256 + ((c ^ (row & 7)) << 3)] = v;
    }
  }

  f32x4 acc[4][8];
  #pragma unroll
  for (int m = 0; m < 4; ++m)
    #pragma unroll
    for (int c = 0; c < 8; ++c)
      acc[m][c] = (f32x4){0.f, 0.f, 0.f, 0.f};

  const int g = lane >> 4;
  const int ln = lane & 15;

  for (int step = 0; step < 8; ++step){
    __syncthreads();                       // prev step's reads of W slice done
    if (USE_WS){
      // wave stages its 8KB quarter of the 32KB slice image, linear, 16B/lane
      const unsigned short* src = wbf + step * 16384 + w * 4096;
      unsigned short* dst = &lds[16384 + w * 4096];
      #pragma unroll
      for (int i = 0; i < 8; ++i){
        __builtin_amdgcn_global_load_lds(
          (const __attribute__((address_space(1))) unsigned*)(src + i * 512 + lane * 8),
          (__attribute__((address_space(3))) unsigned*)(dst + i * 512),
          16, 0, 0);
      }
      asm volatile("s_waitcnt vmcnt(0)" ::: "memory");
    } else {
      // fallback: convert f32 W on the fly into the same slice image
      #pragma unroll
      for (int i = 0; i < 8; ++i){
        int lin = i * 256 + t;             // chunk (gg, c)
        int gg = lin >> 9;
        int c = lin & 511;
        int kb = step * 32 + gg * 8;
        const float* sp = (c < 256) ? (Wl + kb * 256 + c) : (Wr + kb * 256 + (c - 256));
        bf16x8 v;
        #pragma unroll
        for (int jj = 0; jj < 8; ++jj) v[jj] = f2bf(sp[jj * 256]);
        *(bf16x8*)&lds[16384 + lin * 8] = v;
      }
    }
    __syncthreads();

    // fragments: A/B both use k-slot mapping k' = g*8 + j  (consistent => correct
    // regardless of the HW's physical K permutation; C/D layout is HW-verified)
    bf16x8 af[4], bfr[8];
    #pragma unroll
    for (int m = 0; m < 4; ++m){
      int row = m * 16 + ln;
      int chunk = step * 4 + g;
      af[m] = *(const bf16x8*)&lds[row * 256 + ((chunk ^ (row & 7)) << 3)];
    }
    #pragma unroll
    for (int c = 0; c < 8; ++c){
      int col = w * 128 + c * 16 + ln;
      bfr[c] = *(const bf16x8*)&lds[16384 + g * 4096 + col * 8];
    }
    #pragma unroll
    for (int m = 0; m < 4; ++m)
      #pragma unroll
      for (int c = 0; c < 8; ++c)
        acc[m][c] = __builtin_amdgcn_mfma_f32_16x16x32_bf16(af[m], bfr[c], acc[m][c], 0, 0, 0);
  }
  __syncthreads();

  // ---- write g tile [64][512] bf16 into LDS (C layout: row=(lane>>4)*4+j, col=lane&15)
  #pragma unroll
  for (int m = 0; m < 4; ++m)
    #pragma unroll
    for (int c = 0; c < 8; ++c){
      int col = w * 128 + c * 16 + ln;
      #pragma unroll
      for (int j = 0; j < 4; ++j){
        int row = m * 16 + g * 4 + j;
        lds[row * 512 + col] = f2bf(acc[m][c][j]);
      }
    }
  __syncthreads();

  // ---- attention + LN: wave w handles local batches w*4 .. w*4+3, sequentially
  const int i_ = lane >> 4;          // e-phase roles: lane = i*16 + j*4 + h
  const int j_ = (lane >> 2) & 3;
  const int h_ = lane & 3;
  const int c0 = (lane & 15) * 16;   // h'-phase: lane owns row i_, cols c0..c0+15
  const int h2 = (lane & 15) >> 2;   // head of that col range

  float4 gmv[4], btv[4];
  #pragma unroll
  for (int q = 0; q < 4; ++q){
    gmv[q] = *(const float4*)(gmw + c0 + q * 4);
    btv[q] = *(const float4*)(btw + c0 + q * 4);
  }

  for (int p = 0; p < 4; ++p){
    int bb = w * 4 + p;
    // e[i][j][h] = sum_d leaky(g_l[i][h*64+d] + g_r[j][h*64+d]) * a[h][d] + eb[i][j]
    float e = 0.f;
    {
      const int rl = (bb * 4 + i_) * 512 + h_ * 64;
      const int rr = (bb * 4 + j_) * 512 + 256 + h_ * 64;
      #pragma unroll
      for (int d8 = 0; d8 < 8; ++d8){
        bf16x8 gl = *(const bf16x8*)&lds[rl + d8 * 8];
        bf16x8 gr = *(const bf16x8*)&lds[rr + d8 * 8];
        #pragma unroll
        for (int u = 0; u < 8; ++u){
          float x = bf2f((unsigned short)gl[u]) + bf2f((unsigned short)gr[u]);
          x = (x >= 0.f) ? x : SLOPE * x;
          e = fmaf(x, a_s[h_ * 64 + d8 * 8 + u], e);
        }
      }
      e += eb_s[i_ * 4 + j_];
    }
    // softmax over j (j lives in lane bits 2..3)
    float mx = fmaxf(e, __shfl_xor(e, 4));
    mx = fmaxf(mx, __shfl_xor(mx, 8));
    float pr = __expf(e - mx);
    float sm = pr + __shfl_xor(pr, 4);
    sm += __shfl_xor(sm, 8);
    float alpha = pr / sm;

    // h'[i][c] = sum_j alpha[i][j][h(c)] * g_r[j][c]
    float hp[16];
    #pragma unroll
    for (int u = 0; u < 16; ++u) hp[u] = 0.f;
    #pragma unroll
    for (int j = 0; j < 4; ++j){
      float aj = __shfl(alpha, (lane & 48) + j * 4 + h2);
      const int rb = (bb * 4 + j) * 512 + 256 + c0;
      bf16x8 v0 = *(const bf16x8*)&lds[rb];
      bf16x8 v1 = *(const bf16x8*)&lds[rb + 8];
      #pragma unroll
      for (int u = 0; u < 8; ++u){
        hp[u]     = fmaf(aj, bf2f((unsigned short)v0[u]), hp[u]);
        hp[u + 8] = fmaf(aj, bf2f((unsigned short)v1[u]), hp[u + 8]);
      }
    }
    // LayerNorm over the 256 cols of row i_ (16 lanes share a row: xor 1,2,4,8)
    float s1 = 0.f, s2 = 0.f;
    #pragma unroll
    for (int u = 0; u < 16; ++u){ s1 += hp[u]; s2 = fmaf(hp[u], hp[u], s2); }
    #pragma unroll
    for (int mask = 1; mask <= 8; mask <<= 1){
      s1 += __shfl_xor(s1, mask);
      s2 += __shfl_xor(s2, mask);
    }
    float mu = s1 * (1.f / 256.f);
    float var = s2 * (1.f / 256.f) - mu * mu;
    float inv = rsqrtf(var + LN_EPS);

    float* op = out + (((size_t)(b0 + bb)) * 4 + i_) * 256 + c0;
    #pragma unroll
    for (int q = 0; q < 4; ++q){
      float4 o;
      const float* gq = (const float*)&gmv[q];
      const float* bq = (const float*)&btv[q];
      o.x = fmaf((hp[q*4+0] - mu) * inv, gq[0], bq[0]);
      o.y = fmaf((hp[q*4+1] - mu) * inv, gq[1], bq[1]);
      o.z = fmaf((hp[q*4+2] - mu) * inv, gq[2], bq[2]);
      o.w = fmaf((hp[q*4+3] - mu) * inv, gq[3], bq[3]);
      *(float4*)(op + q * 4) = o;
    }
  }
}

extern "C" void kernel_launch(void* const* d_in, const int* in_sizes, int n_in,
                              void* d_out, int out_size, void* d_ws, size_t ws_size,
                              hipStream_t stream){
  const float* h  = (const float*)d_in[0];
  const float* eb = (const float*)d_in[1];
  const float* Wl = (const float*)d_in[2];
  const float* Wr = (const float*)d_in[3];
  const float* a  = (const float*)d_in[4];
  const float* gm = (const float*)d_in[5];
  const float* bt = (const float*)d_in[6];
  float* out = (float*)d_out;
  (void)n_in; (void)out_size;

  int B = in_sizes[0] / 1024;        // (B, 4, 256) f32
  int nblk = B / 16;

  if (ws_size >= 262144){
    unsigned short* wbf = (unsigned short*)d_ws;
    wconv_kernel<<<512, 256, 0, stream>>>(Wl, Wr, wbf);
    gat_fused<true><<<nblk, 256, 0, stream>>>(h, eb, Wl, Wr, a, gm, bt, wbf, out);
  } else {
    gat_fused<false><<<nblk, 256, 0, stream>>>(h, eb, Wl, Wr, a, gm, bt, nullptr, out);
  }
}

// Round 4
// 112.828 us; speedup vs baseline: 1.0585x; 1.0585x over previous
//
#include <hip/hip_runtime.h>

typedef short bf16x8 __attribute__((ext_vector_type(8)));
typedef float f32x4 __attribute__((ext_vector_type(4)));

#define LN_EPS 1e-5f
#define SLOPE 0.2f

__device__ __forceinline__ float bf2f(unsigned short s){
  return __uint_as_float(((unsigned)s) << 16);
}
__device__ __forceinline__ unsigned short f2bf(float f){
  unsigned u = __float_as_uint(f);
  u += 0x7fffu + ((u >> 16) & 1u);   // round-to-nearest-even
  return (unsigned short)(u >> 16);
}

// Round-1 verbatim wconv (scalar):
// element ((s*4+g)*512 + c)*8 + j  =  W[k = s*32+g*8+j][c]   (c<256: W_l, else W_r)
__global__ void wconv_kernel(const float* __restrict__ Wl,
                             const float* __restrict__ Wr,
                             unsigned short* __restrict__ wbf){
  int idx = blockIdx.x * 256 + threadIdx.x;   // 0..131071
  int j = idx & 7;
  int c = (idx >> 3) & 511;
  int g = (idx >> 12) & 3;
  int s = idx >> 14;
  int k = s * 32 + g * 8 + j;
  float v = (c < 256) ? Wl[k * 256 + c] : Wr[k * 256 + (c - 256)];
  wbf[idx] = f2bf(v);
}

// Round-1 structure verbatim; ONLY change: W fragments read directly from the
// L2-resident wbf image (no per-step LDS staging, no vmcnt drains, no k-loop barriers).
template<bool USE_WS>
__global__ __launch_bounds__(256, 2)
void gat_fused(const float* __restrict__ hin, const float* __restrict__ ebias,
               const float* __restrict__ Wl, const float* __restrict__ Wr,
               const float* __restrict__ avec, const float* __restrict__ gmw,
               const float* __restrict__ btw, const unsigned short* __restrict__ wbf,
               float* __restrict__ out){
  // GEMM phase: h tile [64][256] bf16 (32KB, XOR-swizzled) in lds[0..16384)
  // attn phase: g tile [64][512] bf16 (64KB) overlays all of lds (after barrier)
  __shared__ __align__(16) unsigned short lds[32768];
  __shared__ float a_s[256];
  __shared__ float eb_s[16];
  const int t = threadIdx.x;
  const int lane = t & 63;
  const int w = t >> 6;
  const int b0 = blockIdx.x * 16;

  a_s[t] = avec[t];
  if (t < 16) eb_s[t] = ebias[t];

  // ---- stage h tile (64 rows x 256 k) f32->bf16, XOR-swizzled by row&7 (16B units)
  {
    const float* hb = hin + (size_t)b0 * 1024;
    #pragma unroll
    for (int it = 0; it < 8; ++it){
      int q = it * 256 + t;          // 16B-chunk id, 2048 total
      int row = q >> 5;
      int c = q & 31;
      const float* src = hb + row * 256 + c * 8;
      float4 f0 = *(const float4*)src;
      float4 f1 = *(const float4*)(src + 4);
      bf16x8 v;
      v[0]=f2bf(f0.x); v[1]=f2bf(f0.y); v[2]=f2bf(f0.z); v[3]=f2bf(f0.w);
      v[4]=f2bf(f1.x); v[5]=f2bf(f1.y); v[6]=f2bf(f1.z); v[7]=f2bf(f1.w);
      *(bf16x8*)&lds[row * 256 + ((c ^ (row & 7)) << 3)] = v;
    }
  }
  __syncthreads();

  f32x4 acc[4][8];
  #pragma unroll
  for (int m = 0; m < 4; ++m)
    #pragma unroll
    for (int c = 0; c < 8; ++c)
      acc[m][c] = (f32x4){0.f, 0.f, 0.f, 0.f};

  const int g = lane >> 4;
  const int ln = lane & 15;

  for (int step = 0; step < 8; ++step){
    // fragments: A/B both use k-slot mapping k' = g*8 + j (consistent => correct)
    bf16x8 af[4], bfr[8];
    #pragma unroll
    for (int m = 0; m < 4; ++m){
      int row = m * 16 + ln;
      int chunk = step * 4 + g;
      af[m] = *(const bf16x8*)&lds[row * 256 + ((chunk ^ (row & 7)) << 3)];
    }
    if constexpr (USE_WS){
      // identical values to round-1's staged copy: lds_w[g*4096 + col*8] == wbf[step*16384 + g*4096 + col*8]
      const unsigned short* wp = wbf + (size_t)step * 16384 + (size_t)g * 4096
                               + (size_t)(w * 128 + ln) * 8;
      #pragma unroll
      for (int c = 0; c < 8; ++c)
        bfr[c] = *(const bf16x8*)(wp + c * 128);
    } else {
      #pragma unroll
      for (int c = 0; c < 8; ++c){
        int col = w * 128 + c * 16 + ln;
        const float* sp = (col < 256) ? (Wl + col) : (Wr + (col - 256));
        #pragma unroll
        for (int j = 0; j < 8; ++j)
          bfr[c][j] = f2bf(sp[(step * 32 + g * 8 + j) * 256]);
      }
    }
    #pragma unroll
    for (int m = 0; m < 4; ++m)
      #pragma unroll
      for (int c = 0; c < 8; ++c)
        acc[m][c] = __builtin_amdgcn_mfma_f32_16x16x32_bf16(af[m], bfr[c], acc[m][c], 0, 0, 0);
  }
  __syncthreads();

  // ---- write g tile [64][512] bf16 into LDS (C layout: row=(lane>>4)*4+j, col=lane&15)
  #pragma unroll
  for (int m = 0; m < 4; ++m)
    #pragma unroll
    for (int c = 0; c < 8; ++c){
      int col = w * 128 + c * 16 + ln;
      #pragma unroll
      for (int j = 0; j < 4; ++j){
        int row = m * 16 + g * 4 + j;
        lds[row * 512 + col] = f2bf(acc[m][c][j]);
      }
    }
  __syncthreads();

  // ---- attention + LN: wave w handles local batches w*4 .. w*4+3, sequentially
  const int i_ = lane >> 4;          // e-phase roles: lane = i*16 + j*4 + h
  const int j_ = (lane >> 2) & 3;
  const int h_ = lane & 3;
  const int c0 = (lane & 15) * 16;   // h'-phase: lane owns row i_, cols c0..c0+15
  const int h2 = (lane & 15) >> 2;   // head of that col range

  float4 gmv[4], btv[4];
  #pragma unroll
  for (int q = 0; q < 4; ++q){
    gmv[q] = *(const float4*)(gmw + c0 + q * 4);
    btv[q] = *(const float4*)(btw + c0 + q * 4);
  }

  for (int p = 0; p < 4; ++p){
    int bb = w * 4 + p;
    // e[i][j][h] = sum_d leaky(g_l[i][h*64+d] + g_r[j][h*64+d]) * a[h][d] + eb[i][j]
    float e = 0.f;
    {
      const int rl = (bb * 4 + i_) * 512 + h_ * 64;
      const int rr = (bb * 4 + j_) * 512 + 256 + h_ * 64;
      #pragma unroll
      for (int d8 = 0; d8 < 8; ++d8){
        bf16x8 gl = *(const bf16x8*)&lds[rl + d8 * 8];
        bf16x8 gr = *(const bf16x8*)&lds[rr + d8 * 8];
        #pragma unroll
        for (int u = 0; u < 8; ++u){
          float x = bf2f((unsigned short)gl[u]) + bf2f((unsigned short)gr[u]);
          x = (x >= 0.f) ? x : SLOPE * x;
          e = fmaf(x, a_s[h_ * 64 + d8 * 8 + u], e);
        }
      }
      e += eb_s[i_ * 4 + j_];
    }
    // softmax over j (j lives in lane bits 2..3)
    float mx = fmaxf(e, __shfl_xor(e, 4));
    mx = fmaxf(mx, __shfl_xor(mx, 8));
    float pr = __expf(e - mx);
    float sm = pr + __shfl_xor(pr, 4);
    sm += __shfl_xor(sm, 8);
    float alpha = pr / sm;

    // h'[i][c] = sum_j alpha[i][j][h(c)] * g_r[j][c]
    float hp[16];
    #pragma unroll
    for (int u = 0; u < 16; ++u) hp[u] = 0.f;
    #pragma unroll
    for (int j = 0; j < 4; ++j){
      float aj = __shfl(alpha, (lane & 48) + j * 4 + h2);
      const int rb = (bb * 4 + j) * 512 + 256 + c0;
      bf16x8 v0 = *(const bf16x8*)&lds[rb];
      bf16x8 v1 = *(const bf16x8*)&lds[rb + 8];
      #pragma unroll
      for (int u = 0; u < 8; ++u){
        hp[u]     = fmaf(aj, bf2f((unsigned short)v0[u]), hp[u]);
        hp[u + 8] = fmaf(aj, bf2f((unsigned short)v1[u]), hp[u + 8]);
      }
    }
    // LayerNorm over the 256 cols of row i_ (16 lanes share a row: xor 1,2,4,8)
    float s1 = 0.f, s2 = 0.f;
    #pragma unroll
    for (int u = 0; u < 16; ++u){ s1 += hp[u]; s2 = fmaf(hp[u], hp[u], s2); }
    #pragma unroll
    for (int mask = 1; mask <= 8; mask <<= 1){
      s1 += __shfl_xor(s1, mask);
      s2 += __shfl_xor(s2, mask);
    }
    float mu = s1 * (1.f / 256.f);
    float var = s2 * (1.f / 256.f) - mu * mu;
    float inv = rsqrtf(var + LN_EPS);

    float* op = out + (((size_t)(b0 + bb)) * 4 + i_) * 256 + c0;
    #pragma unroll
    for (int q = 0; q < 4; ++q){
      float4 o;
      const float* gq = (const float*)&gmv[q];
      const float* bq = (const float*)&btv[q];
      o.x = fmaf((hp[q*4+0] - mu) * inv, gq[0], bq[0]);
      o.y = fmaf((hp[q*4+1] - mu) * inv, gq[1], bq[1]);
      o.z = fmaf((hp[q*4+2] - mu) * inv, gq[2], bq[2]);
      o.w = fmaf((hp[q*4+3] - mu) * inv, gq[3], bq[3]);
      *(float4*)(op + q * 4) = o;
    }
  }
}

extern "C" void kernel_launch(void* const* d_in, const int* in_sizes, int n_in,
                              void* d_out, int out_size, void* d_ws, size_t ws_size,
                              hipStream_t stream){
  const float* h  = (const float*)d_in[0];
  const float* eb = (const float*)d_in[1];
  const float* Wl = (const float*)d_in[2];
  const float* Wr = (const float*)d_in[3];
  const float* a  = (const float*)d_in[4];
  const float* gm = (const float*)d_in[5];
  const float* bt = (const float*)d_in[6];
  float* out = (float*)d_out;
  (void)n_in; (void)out_size;

  int B = in_sizes[0] / 1024;        // (B, 4, 256) f32
  int nblk = B / 16;

  if (ws_size >= 262144){
    unsigned short* wbf = (unsigned short*)d_ws;
    wconv_kernel<<<512, 256, 0, stream>>>(Wl, Wr, wbf);
    gat_fused<true><<<nblk, 256, 0, stream>>>(h, eb, Wl, Wr, a, gm, bt, wbf, out);
  } else {
    gat_fused<false><<<nblk, 256, 0, stream>>>(h, eb, Wl, Wr, a, gm, bt, nullptr, out);
  }
}